// Round 2
// baseline (335.274 us; speedup 1.0000x reference)
//
#include <hip/hip_runtime.h>

// SPU(z) = z^2 - 0.5           for z >= 0
//        = sigmoid(-z) - 1     for z <  0
// sigmoid(-z) - 1 = -e^z/(1+e^z)   (cancellation-free form, e^z in (0,1) for z<0)
//
// Fast-path transcendentals: v_exp_f32 computes 2^x, so e^z = 2^(z*log2e).
// v_rcp_f32 replaces the full-precision divide sequence. Both ~1 ulp;
// absmax headroom vs threshold is ~30x, and for z>=0 the (possibly NaN at
// e=inf) negative-branch value is discarded by the select.
__device__ __forceinline__ float spu(float z) {
    const float LOG2E = 1.44269504088896340736f;
    float e   = __builtin_amdgcn_exp2f(z * LOG2E);   // v_exp_f32
    float neg = -e * __builtin_amdgcn_rcpf(1.0f + e); // v_rcp_f32
    float pos = fmaf(z, z, -0.5f);
    return (z >= 0.0f) ? pos : neg;
}

__global__ __launch_bounds__(256)
void spu_box_kernel(const float* __restrict__ x,
                    const float* __restrict__ l_in,
                    const float* __restrict__ u_in,
                    float* __restrict__ x_out,
                    float* __restrict__ l_out,
                    float* __restrict__ u_out,
                    int n4)                  // number of float4 groups
{
    int i = blockIdx.x * blockDim.x + threadIdx.x;
    if (i >= n4) return;

    float4 xv = ((const float4*)x)[i];
    float4 lv = ((const float4*)l_in)[i];
    float4 uv = ((const float4*)u_in)[i];

    float4 xo, lo, uo;

    #pragma unroll
    for (int k = 0; k < 4; ++k) {
        float xs = ((const float*)&xv)[k];
        float ls = ((const float*)&lv)[k];
        float us = ((const float*)&uv)[k];

        float sx = spu(xs);
        float sl = spu(ls);
        float su = spu(us);

        // l_out: l>=0 -> spu(l); else u<=0 -> spu(u); else -0.5
        float lres = (ls >= 0.0f) ? sl : ((us <= 0.0f) ? su : -0.5f);
        // u_out: u<=0 -> spu(l); else spu(u)
        float ures = (us <= 0.0f) ? sl : su;

        ((float*)&xo)[k] = sx;
        ((float*)&lo)[k] = lres;
        ((float*)&uo)[k] = ures;
    }

    ((float4*)x_out)[i] = xo;
    ((float4*)l_out)[i] = lo;
    ((float4*)u_out)[i] = uo;
}

// Scalar tail (n not divisible by 4) — not hit for DIM=16777216 but kept safe.
__global__ void spu_box_tail(const float* __restrict__ x,
                             const float* __restrict__ l_in,
                             const float* __restrict__ u_in,
                             float* __restrict__ x_out,
                             float* __restrict__ l_out,
                             float* __restrict__ u_out,
                             int start, int n)
{
    int i = start + blockIdx.x * blockDim.x + threadIdx.x;
    if (i >= n) return;
    float xs = x[i], ls = l_in[i], us = u_in[i];
    float sx = spu(xs), sl = spu(ls), su = spu(us);
    x_out[i] = sx;
    l_out[i] = (ls >= 0.0f) ? sl : ((us <= 0.0f) ? su : -0.5f);
    u_out[i] = (us <= 0.0f) ? sl : su;
}

extern "C" void kernel_launch(void* const* d_in, const int* in_sizes, int n_in,
                              void* d_out, int out_size, void* d_ws, size_t ws_size,
                              hipStream_t stream) {
    const float* x    = (const float*)d_in[0];
    const float* l_in = (const float*)d_in[1];
    const float* u_in = (const float*)d_in[2];

    const int n = in_sizes[0];           // 16777216
    float* out   = (float*)d_out;        // [x_out | l_out | u_out], each n floats
    float* x_out = out;
    float* l_out = out + n;
    float* u_out = out + 2 * (size_t)n;

    const int n4 = n / 4;
    const int block = 256;
    const int grid = (n4 + block - 1) / block;
    spu_box_kernel<<<grid, block, 0, stream>>>(x, l_in, u_in, x_out, l_out, u_out, n4);

    const int tail_start = n4 * 4;
    if (tail_start < n) {
        const int tail = n - tail_start;
        spu_box_tail<<<(tail + 63) / 64, 64, 0, stream>>>(x, l_in, u_in,
                                                          x_out, l_out, u_out,
                                                          tail_start, n);
    }
}